// Round 1
// baseline (618.298 us; speedup 1.0000x reference)
//
#include <hip/hip_runtime.h>
#include <hip/hip_bf16.h>

typedef float f32x4 __attribute__((ext_vector_type(4)));
typedef short s16x8 __attribute__((ext_vector_type(8)));

constexpr int C_CLS = 19, V_VIEWS = 10, A_DIM = 256;
constexpr int NROWS = C_CLS * V_VIEWS;        // 190
constexpr int NQ = 38, QSZ = 8192;
constexpr long M_TOTAL = (long)NQ * QSZ;      // 311296
constexpr int COLS_PER_BLOCK = 128;
constexpr int NBLK = (int)(M_TOTAL / COLS_PER_BLOCK);   // 2432
constexpr int CHUNK_COLS = 32;
constexpr int NCHUNK = (int)(M_TOTAL / CHUNK_COLS);     // 9728
constexpr float TINV = 14.285714285714285714f;          // 1/0.07

// RNE float->bf16 (inputs are finite normals; no NaN path needed)
__device__ inline short f2bs(float f) {
    unsigned u = __builtin_bit_cast(unsigned, f);
    unsigned r = (u + 0x7fffu + ((u >> 16) & 1u)) >> 16;
    return (short)r;
}

// ---------------- kernel 0: feat (C,V,A) fp32 -> anchor (192,256) bf16, view-major ----
__global__ __launch_bounds__(256)
void k_anchor(const float* __restrict__ feat, short* __restrict__ anchor)
{
    const int row = blockIdx.x;     // 0..191
    const int t = threadIdx.x;      // 0..255
    float v = 0.f;
    if (row < NROWS) {
        const int c = row % C_CLS, vv = row / C_CLS;
        v = feat[((size_t)c * V_VIEWS + vv) * A_DIM + t];
    }
    anchor[(size_t)row * A_DIM + t] = f2bs(v);
}

// ---------------- kernel 1: GEMM + per-chunk softmax stats -------------------------
// block = 8 waves. wave (mhalf = wid>>2) owns rows [mhalf*96, +96), (cgrp = wid&3)
// owns cols [b*128 + cgrp*32, +32). K = 256 in 8 steps of 32.
__global__ __launch_bounds__(512)
void k_gemm_stats(const float* __restrict__ queue, const short* __restrict__ anchor,
                  const int* __restrict__ label,
                  float* __restrict__ PM, float* __restrict__ PS, float* __restrict__ POS)
{
    const int b    = blockIdx.x;
    const int tid  = threadIdx.x;
    const int lane = tid & 63;
    const int wid  = tid >> 6;
    const int mhalf = wid >> 2;
    const int cgrp  = wid & 3;
    const int l15 = lane & 15;
    const int l4  = lane >> 4;

    const int colbase = b * COLS_PER_BLOCK + cgrp * CHUNK_COLS;

    f32x4 acc[6][2];
    #pragma unroll
    for (int i = 0; i < 6; ++i)
        #pragma unroll
        for (int j = 0; j < 2; ++j)
            acc[i][j] = (f32x4){0.f, 0.f, 0.f, 0.f};

    // A: lane holds A[row = l&15][k = (l>>4)*8 + j]  (bf16, 8 contiguous)
    const short* ap  = anchor + (size_t)(mhalf * 96 + l15) * A_DIM + l4 * 8;
    // B: lane holds B[k = (l>>4)*8 + j][col = l&15] = queue[col][k]
    const float* qp0 = queue + (size_t)(colbase + l15) * A_DIM + l4 * 8;
    const float* qp1 = qp0 + (size_t)16 * A_DIM;

    #pragma unroll
    for (int kk = 0; kk < 8; ++kk) {
        const int ko = kk * 32;
        s16x8 bfr[2];
        {
            f32x4 lo = *(const f32x4*)(qp0 + ko);
            f32x4 hi = *(const f32x4*)(qp0 + ko + 4);
            s16x8 r;
            #pragma unroll
            for (int j = 0; j < 4; ++j) { r[j] = f2bs(lo[j]); r[4 + j] = f2bs(hi[j]); }
            bfr[0] = r;
        }
        {
            f32x4 lo = *(const f32x4*)(qp1 + ko);
            f32x4 hi = *(const f32x4*)(qp1 + ko + 4);
            s16x8 r;
            #pragma unroll
            for (int j = 0; j < 4; ++j) { r[j] = f2bs(lo[j]); r[4 + j] = f2bs(hi[j]); }
            bfr[1] = r;
        }
        s16x8 afr[6];
        #pragma unroll
        for (int mt = 0; mt < 6; ++mt)
            afr[mt] = *(const s16x8*)(ap + (size_t)mt * 16 * A_DIM + ko);
        #pragma unroll
        for (int mt = 0; mt < 6; ++mt)
            #pragma unroll
            for (int nt = 0; nt < 2; ++nt)
                acc[mt][nt] = __builtin_amdgcn_mfma_f32_16x16x32_bf16(
                    afr[mt], bfr[nt], acc[mt][nt], 0, 0, 0);
    }

    // epilogue: D layout col = lane&15, row = (lane>>4)*4 + reg
    const int qb    = b >> 6;         // queue block (0..37) of this tile
    const int chunk = b * 4 + cgrp;   // 32-col chunk index
    #pragma unroll
    for (int mt = 0; mt < 6; ++mt) {
        #pragma unroll
        for (int reg = 0; reg < 4; ++reg) {
            const int row = mhalf * 96 + mt * 16 + l4 * 4 + reg;
            if (row >= NROWS) continue;              // padding rows 190,191
            const int pb = label[row % C_CLS];       // positive queue-block for this row
            float v0 = acc[mt][0][reg] * TINV;
            float v1 = acc[mt][1][reg] * TINV;
            if (pb == qb) {
                // positive block: store raw logits (diagonal handled in finalize)
                const int colw = (b & 63) * COLS_PER_BLOCK + cgrp * CHUNK_COLS + l15;
                POS[(size_t)row * QSZ + colw]      = v0;
                POS[(size_t)row * QSZ + colw + 16] = v1;
                if (l15 == 0) {
                    PM[(size_t)row * NCHUNK + chunk] = -3.0e38f;
                    PS[(size_t)row * NCHUNK + chunk] = 0.f;
                }
            } else {
                // negative chunk: local max + sum(exp) across the 16-lane group
                float m = fmaxf(v0, v1);
                #pragma unroll
                for (int d = 1; d < 16; d <<= 1) m = fmaxf(m, __shfl_xor(m, d, 64));
                float s = __expf(v0 - m) + __expf(v1 - m);
                #pragma unroll
                for (int d = 1; d < 16; d <<= 1) s += __shfl_xor(s, d, 64);
                if (l15 == 0) {
                    PM[(size_t)row * NCHUNK + chunk] = m;
                    PS[(size_t)row * NCHUNK + chunk] = s;
                }
            }
        }
    }
}

// ---------------- kernel 2: per-row finalize + scalar reduce -----------------------
__global__ __launch_bounds__(256)
void k_finalize(const float* __restrict__ PM, const float* __restrict__ PS,
                const float* __restrict__ POS, const int* __restrict__ label,
                float* __restrict__ out)
{
    const int row = blockIdx.x;
    const int t = threadIdx.x, lane = t & 63, w = t >> 6;
    const int pb = label[row % C_CLS];
    __shared__ float  redf[4];
    __shared__ double redd[4], redd2[4];
    __shared__ float  s_gmax, s_S;

    // Phase A: global row max over neg-chunk maxes and stored positive logits
    float m = -3.0e38f;
    for (int j = t; j < NCHUNK; j += 256) m = fmaxf(m, PM[(size_t)row * NCHUNK + j]);
    for (int j = t; j < QSZ;    j += 256) m = fmaxf(m, POS[(size_t)row * QSZ + j]);
    #pragma unroll
    for (int d = 1; d < 64; d <<= 1) m = fmaxf(m, __shfl_xor(m, d, 64));
    if (lane == 0) redf[w] = m;
    __syncthreads();
    if (t == 0) s_gmax = fmaxf(fmaxf(redf[0], redf[1]), fmaxf(redf[2], redf[3]));
    __syncthreads();
    const float gmax = s_gmax;

    // Phase B: neg_sum S = sum_j PS[j] * exp(PM[j] - gmax)
    float s = 0.f;
    for (int j = t; j < NCHUNK; j += 256) {
        float pm = PM[(size_t)row * NCHUNK + j];
        s += PS[(size_t)row * NCHUNK + j] * __expf(pm - gmax);
    }
    #pragma unroll
    for (int d = 1; d < 64; d <<= 1) s += __shfl_xor(s, d, 64);
    if (lane == 0) redf[w] = s;
    __syncthreads();
    if (t == 0) s_S = redf[0] + redf[1] + redf[2] + redf[3];
    __syncthreads();
    const float S = s_S;

    // Phase C: sum over positives of l and log(exp(l)+S), skipping the diagonal
    double sl = 0.0, slg = 0.0;
    for (int j = t; j < QSZ; j += 256) {
        if ((size_t)pb * QSZ + j == (size_t)row) continue;   // self-contrast removal
        float l = POS[(size_t)row * QSZ + j] - gmax;
        sl  += (double)l;
        slg += (double)__logf(__expf(l) + S);
    }
    #pragma unroll
    for (int d = 1; d < 64; d <<= 1) { sl += __shfl_xor(sl, d, 64); slg += __shfl_xor(slg, d, 64); }
    if (lane == 0) { redd[w] = sl; redd2[w] = slg; }
    __syncthreads();
    if (t == 0) {
        double SL  = redd[0] + redd[1] + redd[2] + redd[3];
        double SLG = redd2[0] + redd2[1] + redd2[2] + redd2[3];
        const long dpos = (long)row - (long)pb * QSZ;
        const int cnt = QSZ - ((dpos >= 0 && dpos < QSZ) ? 1 : 0);
        double mlpp = (SL - SLG) / (double)cnt;
        atomicAdd(out, (float)(-mlpp / (2.0 * (double)NROWS)));
    }
}

extern "C" void kernel_launch(void* const* d_in, const int* in_sizes, int n_in,
                              void* d_out, int out_size, void* d_ws, size_t ws_size,
                              hipStream_t stream) {
    const float* feat  = (const float*)d_in[0];   // (19,10,256) fp32
    const int*   label = (const int*)d_in[1];     // (19,) int32
    const float* queue = (const float*)d_in[2];   // (38,8192,256) fp32
    float* out = (float*)d_out;

    char* ws = (char*)d_ws;
    short* anchor = (short*)ws;                                   //  98,304 B
    float* PM  = (float*)(ws + 98304);                            // 190*9728*4 = 7,393,280 B
    float* PS  = (float*)(ws + 98304 + 7393280);                  // 7,393,280 B
    float* POS = (float*)(ws + 98304 + 2 * 7393280);              // 190*8192*4 = 6,225,920 B
    // total ws: 21,110,784 B

    hipMemsetAsync(out, 0, sizeof(float), stream);
    k_anchor<<<192, 256, 0, stream>>>(feat, anchor);
    k_gemm_stats<<<NBLK, 512, 0, stream>>>(queue, anchor, label, PM, PS, POS);
    k_finalize<<<NROWS, 256, 0, stream>>>(PM, PS, POS, label, out);
}

// Round 2
// 594.530 us; speedup vs baseline: 1.0400x; 1.0400x over previous
//
#include <hip/hip_runtime.h>
#include <hip/hip_bf16.h>

typedef float f32x4 __attribute__((ext_vector_type(4)));
typedef short s16x8 __attribute__((ext_vector_type(8)));

constexpr int C_CLS = 19, V_VIEWS = 10, A_DIM = 256;
constexpr int NROWS = C_CLS * V_VIEWS;        // 190
constexpr int NQ = 38, QSZ = 8192;
constexpr long M_TOTAL = (long)NQ * QSZ;      // 311296
constexpr int COLS_PER_BLOCK = 128;
constexpr int NBLK = (int)(M_TOTAL / COLS_PER_BLOCK);   // 2432
constexpr int CHUNK_COLS = 32;
constexpr int NCHUNK = (int)(M_TOTAL / CHUNK_COLS);     // 9728
constexpr float TINV = 14.285714285714285714f;          // 1/0.07

// RNE float->bf16 (inputs are finite normals; no NaN path needed)
__device__ inline short f2bs(float f) {
    unsigned u = __builtin_bit_cast(unsigned, f);
    unsigned r = (u + 0x7fffu + ((u >> 16) & 1u)) >> 16;
    return (short)r;
}

__device__ inline s16x8 cvt8(f32x4 lo, f32x4 hi) {
    s16x8 r;
    #pragma unroll
    for (int j = 0; j < 4; ++j) { r[j] = f2bs(lo[j]); r[4 + j] = f2bs(hi[j]); }
    return r;
}

// ---------------- kernel 0: feat (C,V,A) fp32 -> anchor (192,256) bf16, view-major ----
__global__ __launch_bounds__(256)
void k_anchor(const float* __restrict__ feat, short* __restrict__ anchor)
{
    const int row = blockIdx.x;     // 0..191
    const int t = threadIdx.x;      // 0..255
    float v = 0.f;
    if (row < NROWS) {
        const int c = row % C_CLS, vv = row / C_CLS;
        v = feat[((size_t)c * V_VIEWS + vv) * A_DIM + t];
    }
    anchor[(size_t)row * A_DIM + t] = f2bs(v);
}

// ---------------- kernel 1: GEMM + per-chunk softmax stats -------------------------
// block = 8 waves. wave (mhalf = wid>>2) owns rows [mhalf*96, +96), (cgrp = wid&3)
// owns cols [b*128 + cgrp*32, +32). K = 256 in 8 steps of 32.
// launch_bounds(512,4): 4 waves/EU min -> <=128 VGPRs, 2 blocks/CU. This is the
// critical fix: at 64 VGPRs the compiler serialized every 16B B-load (707 GB/s).
__global__ __launch_bounds__(512, 4)
void k_gemm_stats(const float* __restrict__ queue, const short* __restrict__ anchor,
                  const int* __restrict__ label,
                  float* __restrict__ PM, float* __restrict__ PS, float* __restrict__ POS)
{
    const int b    = blockIdx.x;
    const int tid  = threadIdx.x;
    const int lane = tid & 63;
    const int wid  = tid >> 6;
    const int mhalf = wid >> 2;
    const int cgrp  = wid & 3;
    const int l15 = lane & 15;
    const int l4  = lane >> 4;

    const int colbase = b * COLS_PER_BLOCK + cgrp * CHUNK_COLS;

    f32x4 acc[6][2];
    #pragma unroll
    for (int i = 0; i < 6; ++i)
        #pragma unroll
        for (int j = 0; j < 2; ++j)
            acc[i][j] = (f32x4){0.f, 0.f, 0.f, 0.f};

    // A: lane holds A[row = l&15][k = (l>>4)*8 + j]  (bf16, 8 contiguous)
    const short* ap  = anchor + (size_t)(mhalf * 96 + l15) * A_DIM + l4 * 8;
    // B: lane holds B[k = (l>>4)*8 + j][col = l&15] = queue[col][k]
    const float* qp0 = queue + (size_t)(colbase + l15) * A_DIM + l4 * 8;
    const float* qp1 = qp0 + (size_t)16 * A_DIM;

    // depth-1 software pipeline for the HBM-streamed B operand
    f32x4 ra0 = *(const f32x4*)(qp0);
    f32x4 ra1 = *(const f32x4*)(qp0 + 4);
    f32x4 rb0 = *(const f32x4*)(qp1);
    f32x4 rb1 = *(const f32x4*)(qp1 + 4);

    #pragma unroll
    for (int kk = 0; kk < 8; ++kk) {
        const int ko = kk * 32;
        // convert current raw B to bf16 fragments
        s16x8 b0 = cvt8(ra0, ra1);
        s16x8 b1 = cvt8(rb0, rb1);
        // prefetch next K-step's B (no dep on conversions -> stays in flight
        // across this iteration's A-loads + MFMAs)
        if (kk < 7) {
            const int kn = ko + 32;
            ra0 = *(const f32x4*)(qp0 + kn);
            ra1 = *(const f32x4*)(qp0 + kn + 4);
            rb0 = *(const f32x4*)(qp1 + kn);
            rb1 = *(const f32x4*)(qp1 + kn + 4);
        }
        s16x8 afr[6];
        #pragma unroll
        for (int mt = 0; mt < 6; ++mt)
            afr[mt] = *(const s16x8*)(ap + (size_t)mt * 16 * A_DIM + ko);
        #pragma unroll
        for (int mt = 0; mt < 6; ++mt) {
            acc[mt][0] = __builtin_amdgcn_mfma_f32_16x16x32_bf16(afr[mt], b0, acc[mt][0], 0, 0, 0);
            acc[mt][1] = __builtin_amdgcn_mfma_f32_16x16x32_bf16(afr[mt], b1, acc[mt][1], 0, 0, 0);
        }
    }

    // epilogue: D layout col = lane&15, row = (lane>>4)*4 + reg
    const int qb    = b >> 6;         // queue block (0..37) of this tile
    const int chunk = b * 4 + cgrp;   // 32-col chunk index
    #pragma unroll
    for (int mt = 0; mt < 6; ++mt) {
        #pragma unroll
        for (int reg = 0; reg < 4; ++reg) {
            const int row = mhalf * 96 + mt * 16 + l4 * 4 + reg;
            if (row >= NROWS) continue;              // padding rows 190,191
            const int pb = label[row % C_CLS];       // positive queue-block for this row
            float v0 = acc[mt][0][reg] * TINV;
            float v1 = acc[mt][1][reg] * TINV;
            if (pb == qb) {
                // positive block: store raw logits (diagonal handled in finalize)
                const int colw = (b & 63) * COLS_PER_BLOCK + cgrp * CHUNK_COLS + l15;
                POS[(size_t)row * QSZ + colw]      = v0;
                POS[(size_t)row * QSZ + colw + 16] = v1;
                if (l15 == 0) {
                    PM[(size_t)row * NCHUNK + chunk] = -3.0e38f;
                    PS[(size_t)row * NCHUNK + chunk] = 0.f;
                }
            } else {
                // negative chunk: local max + sum(exp) across the 16-lane group
                float m = fmaxf(v0, v1);
                #pragma unroll
                for (int d = 1; d < 16; d <<= 1) m = fmaxf(m, __shfl_xor(m, d, 64));
                float s = __expf(v0 - m) + __expf(v1 - m);
                #pragma unroll
                for (int d = 1; d < 16; d <<= 1) s += __shfl_xor(s, d, 64);
                if (l15 == 0) {
                    PM[(size_t)row * NCHUNK + chunk] = m;
                    PS[(size_t)row * NCHUNK + chunk] = s;
                }
            }
        }
    }
}

// ---------------- kernel 2: per-row finalize + scalar reduce -----------------------
// 1024 threads + float4 loads: ~10 dependent load rounds instead of ~140.
__global__ __launch_bounds__(1024)
void k_finalize(const float* __restrict__ PM, const float* __restrict__ PS,
                const float* __restrict__ POS, const int* __restrict__ label,
                float* __restrict__ out)
{
    const int row = blockIdx.x;
    const int t = threadIdx.x, lane = t & 63, w = t >> 6;   // w in 0..15
    const int pb = label[row % C_CLS];
    __shared__ float  redf[16];
    __shared__ double redd[16], redd2[16];
    __shared__ float  s_gmax, s_S;

    const f32x4* PM4  = (const f32x4*)(PM  + (size_t)row * NCHUNK);
    const f32x4* PS4  = (const f32x4*)(PS  + (size_t)row * NCHUNK);
    const f32x4* POS4 = (const f32x4*)(POS + (size_t)row * QSZ);
    constexpr int NC4 = NCHUNK / 4;   // 2432
    constexpr int NP4 = QSZ / 4;      // 2048

    // Phase A: global row max over neg-chunk maxes and stored positive logits
    float m = -3.0e38f;
    for (int j = t; j < NC4; j += 1024) {
        f32x4 v = PM4[j];
        m = fmaxf(m, fmaxf(fmaxf(v[0], v[1]), fmaxf(v[2], v[3])));
    }
    for (int j = t; j < NP4; j += 1024) {
        f32x4 v = POS4[j];
        m = fmaxf(m, fmaxf(fmaxf(v[0], v[1]), fmaxf(v[2], v[3])));
    }
    #pragma unroll
    for (int d = 1; d < 64; d <<= 1) m = fmaxf(m, __shfl_xor(m, d, 64));
    if (lane == 0) redf[w] = m;
    __syncthreads();
    if (t == 0) {
        float g = redf[0];
        #pragma unroll
        for (int i = 1; i < 16; ++i) g = fmaxf(g, redf[i]);
        s_gmax = g;
    }
    __syncthreads();
    const float gmax = s_gmax;

    // Phase B: neg_sum S = sum_j PS[j] * exp(PM[j] - gmax)
    float s = 0.f;
    for (int j = t; j < NC4; j += 1024) {
        f32x4 pm = PM4[j], ps = PS4[j];
        s += ps[0] * __expf(pm[0] - gmax) + ps[1] * __expf(pm[1] - gmax)
           + ps[2] * __expf(pm[2] - gmax) + ps[3] * __expf(pm[3] - gmax);
    }
    #pragma unroll
    for (int d = 1; d < 64; d <<= 1) s += __shfl_xor(s, d, 64);
    if (lane == 0) redf[w] = s;
    __syncthreads();
    if (t == 0) {
        float g = 0.f;
        #pragma unroll
        for (int i = 0; i < 16; ++i) g += redf[i];
        s_S = g;
    }
    __syncthreads();
    const float S = s_S;

    // Phase C: sum over positives of l and log(exp(l)+S), skipping the diagonal
    const long dpos = (long)row - (long)pb * QSZ;
    const int diag = (dpos >= 0 && dpos < QSZ) ? (int)dpos : -1;
    double sl = 0.0, slg = 0.0;
    for (int j = t; j < NP4; j += 1024) {
        f32x4 v = POS4[j];
        #pragma unroll
        for (int e = 0; e < 4; ++e) {
            const int col = 4 * j + e;
            if (col == diag) continue;
            float l = v[e] - gmax;
            sl  += (double)l;
            slg += (double)__logf(__expf(l) + S);
        }
    }
    #pragma unroll
    for (int d = 1; d < 64; d <<= 1) { sl += __shfl_xor(sl, d, 64); slg += __shfl_xor(slg, d, 64); }
    if (lane == 0) { redd[w] = sl; redd2[w] = slg; }
    __syncthreads();
    if (t == 0) {
        double SL = 0.0, SLG = 0.0;
        #pragma unroll
        for (int i = 0; i < 16; ++i) { SL += redd[i]; SLG += redd2[i]; }
        const int cnt = QSZ - ((diag >= 0) ? 1 : 0);
        double mlpp = (SL - SLG) / (double)cnt;
        atomicAdd(out, (float)(-mlpp / (2.0 * (double)NROWS)));
    }
}

extern "C" void kernel_launch(void* const* d_in, const int* in_sizes, int n_in,
                              void* d_out, int out_size, void* d_ws, size_t ws_size,
                              hipStream_t stream) {
    const float* feat  = (const float*)d_in[0];   // (19,10,256) fp32
    const int*   label = (const int*)d_in[1];     // (19,) int32
    const float* queue = (const float*)d_in[2];   // (38,8192,256) fp32
    float* out = (float*)d_out;

    char* ws = (char*)d_ws;
    short* anchor = (short*)ws;                                   //  98,304 B
    float* PM  = (float*)(ws + 98304);                            // 7,393,280 B
    float* PS  = (float*)(ws + 98304 + 7393280);                  // 7,393,280 B
    float* POS = (float*)(ws + 98304 + 2 * 7393280);              // 6,225,920 B

    hipMemsetAsync(out, 0, sizeof(float), stream);
    k_anchor<<<192, 256, 0, stream>>>(feat, anchor);
    k_gemm_stats<<<NBLK, 512, 0, stream>>>(queue, anchor, label, PM, PS, POS);
    k_finalize<<<NROWS, 1024, 0, stream>>>(PM, PS, POS, label, out);
}